// Round 3
// baseline (1098.708 us; speedup 1.0000x reference)
//
#include <hip/hip_runtime.h>
#include <hip/hip_bf16.h>

namespace {
constexpr int kN = 50000;   // nodes
constexpr int kE = 250000;  // edges
constexpr int kG = 2500;    // graphs
constexpr int NB = 16;      // nodes per conv block

__device__ __forceinline__ float sigmoidf_(float x) { return 1.0f / (1.0f + expf(-x)); }

// starts[g] = first node index with batch[n] >= g (batch is sorted). g in [0, kG].
__global__ void k_starts(const int* __restrict__ batch, int* __restrict__ starts) {
  int g = blockIdx.x * blockDim.x + threadIdx.x;
  if (g > kG) return;
  int lo = 0, hi = kN;
  while (lo < hi) {
    int mid = (lo + hi) >> 1;
    if (batch[mid] < g) lo = mid + 1; else hi = mid;
  }
  starts[g] = lo;
}

// h[n,:] = relu(x[n,:] @ lin_w + lin_b)   [N,32] = [N,32]@[32,32]
__global__ __launch_bounds__(256) void k_node_init(const float* __restrict__ x,
                                                   const float* __restrict__ lin_w,
                                                   const float* __restrict__ lin_b,
                                                   float* __restrict__ h) {
  __shared__ float ws[32 * 32];
  __shared__ float bs[32];
  for (int i = threadIdx.x; i < 1024; i += 256) ws[i] = lin_w[i];
  if (threadIdx.x < 32) bs[threadIdx.x] = lin_b[threadIdx.x];
  __syncthreads();
  int n = blockIdx.x * 256 + threadIdx.x;
  if (n >= kN) return;
  float xv[32];
  const float4* xp = (const float4*)(x + (size_t)n * 32);
#pragma unroll
  for (int i = 0; i < 8; ++i) {
    float4 v = xp[i];
    xv[4 * i + 0] = v.x; xv[4 * i + 1] = v.y; xv[4 * i + 2] = v.z; xv[4 * i + 3] = v.w;
  }
  float acc[32];
#pragma unroll
  for (int o = 0; o < 32; ++o) acc[o] = bs[o];
  for (int i = 0; i < 32; ++i) {
    float a = xv[i];
    const float4* wr = (const float4*)&ws[i * 32];
#pragma unroll
    for (int o4 = 0; o4 < 8; ++o4) {
      float4 w = wr[o4];
      acc[4 * o4 + 0] = fmaf(a, w.x, acc[4 * o4 + 0]);
      acc[4 * o4 + 1] = fmaf(a, w.y, acc[4 * o4 + 1]);
      acc[4 * o4 + 2] = fmaf(a, w.z, acc[4 * o4 + 2]);
      acc[4 * o4 + 3] = fmaf(a, w.w, acc[4 * o4 + 3]);
    }
  }
  float4* hp = (float4*)(h + (size_t)n * 32);
#pragma unroll
  for (int i = 0; i < 8; ++i) {
    float4 v;
    v.x = fmaxf(acc[4 * i + 0], 0.f);
    v.y = fmaxf(acc[4 * i + 1], 0.f);
    v.z = fmaxf(acc[4 * i + 2], 0.f);
    v.w = fmaxf(acc[4 * i + 3], 0.f);
    hp[i] = v;
  }
}

// eh[e,:] = relu(edge_attr[e,:] @ e_w1 + e_b1)   [E,64] = [E,16]@[16,64]
__global__ __launch_bounds__(256) void k_edge_h(const float* __restrict__ ea,
                                                const float* __restrict__ w1,
                                                const float* __restrict__ b1,
                                                float* __restrict__ eh) {
  __shared__ float ws[16 * 64];
  __shared__ float bs[64];
  for (int i = threadIdx.x; i < 1024; i += 256) ws[i] = w1[i];
  if (threadIdx.x < 64) bs[threadIdx.x] = b1[threadIdx.x];
  __syncthreads();
  int e = blockIdx.x * 256 + threadIdx.x;
  if (e >= kE) return;
  float av[16];
  const float4* ap = (const float4*)(ea + (size_t)e * 16);
#pragma unroll
  for (int i = 0; i < 4; ++i) {
    float4 v = ap[i];
    av[4 * i + 0] = v.x; av[4 * i + 1] = v.y; av[4 * i + 2] = v.z; av[4 * i + 3] = v.w;
  }
  float acc[64];
#pragma unroll
  for (int o = 0; o < 64; ++o) acc[o] = bs[o];
  for (int i = 0; i < 16; ++i) {
    float a = av[i];
    const float4* wr = (const float4*)&ws[i * 64];
#pragma unroll
    for (int o4 = 0; o4 < 16; ++o4) {
      float4 w = wr[o4];
      acc[4 * o4 + 0] = fmaf(a, w.x, acc[4 * o4 + 0]);
      acc[4 * o4 + 1] = fmaf(a, w.y, acc[4 * o4 + 1]);
      acc[4 * o4 + 2] = fmaf(a, w.z, acc[4 * o4 + 2]);
      acc[4 * o4 + 3] = fmaf(a, w.w, acc[4 * o4 + 3]);
    }
  }
  float4* op = (float4*)(eh + (size_t)e * 64);
#pragma unroll
  for (int i = 0; i < 16; ++i) {
    float4 v;
    v.x = fmaxf(acc[4 * i + 0], 0.f);
    v.y = fmaxf(acc[4 * i + 1], 0.f);
    v.z = fmaxf(acc[4 * i + 2], 0.f);
    v.w = fmaxf(acc[4 * i + 3], 0.f);
    op[i] = v;
  }
}

// degree (by dst, for mean denom) and histogram (by src, for sort) in one pass
__global__ void k_deg_hist(const int* __restrict__ dst, const int* __restrict__ src,
                           float* __restrict__ denom, int* __restrict__ cnt) {
  int e = blockIdx.x * blockDim.x + threadIdx.x;
  if (e < kE) {
    atomicAdd(&denom[dst[e]], 1.0f);
    atomicAdd(&cnt[src[e]], 1);
  }
}

// exclusive scan of cnt[0..kN) -> offs[0..kN], single block of 1024 threads
__global__ __launch_bounds__(1024) void k_scan(const int* __restrict__ cnt, int* __restrict__ offs) {
  __shared__ int wsum[16];
  __shared__ int wpre[16];
  __shared__ int carry_s;
  const int tid = threadIdx.x;
  const int lane = tid & 63, wv = tid >> 6;
  if (tid == 0) carry_s = 0;
  __syncthreads();
  for (int base = 0; base < kN; base += 1024) {
    int i = base + tid;
    int v = (i < kN) ? cnt[i] : 0;
    int x = v;
#pragma unroll
    for (int d = 1; d < 64; d <<= 1) {
      int t = __shfl_up(x, d, 64);
      if (lane >= d) x += t;
    }
    if (lane == 63) wsum[wv] = x;
    __syncthreads();
    if (wv == 0) {
      int y = (lane < 16) ? wsum[lane] : 0;
#pragma unroll
      for (int d = 1; d < 16; d <<= 1) {
        int t = __shfl_up(y, d, 64);
        if (lane >= d && lane < 16) y += t;
      }
      if (lane < 16) wpre[lane] = y - wsum[lane];  // exclusive wave prefix
    }
    __syncthreads();
    int carry = carry_s;
    if (i < kN) offs[i] = carry + wpre[wv] + (x - v);
    __syncthreads();
    if (tid == 0) carry_s = carry + wpre[15] + wsum[15];
    __syncthreads();
  }
  if (tid == 0) offs[kN] = carry_s;
}

__global__ void k_scatter(const int* __restrict__ src, const int* __restrict__ dst,
                          const int* __restrict__ offs, int* __restrict__ cur,
                          int* __restrict__ es_e, int* __restrict__ es_src,
                          int* __restrict__ es_dst) {
  int e = blockIdx.x * blockDim.x + threadIdx.x;
  if (e >= kE) return;
  int s = src[e];
  int pos = offs[s] + atomicAdd(&cur[s], 1);
  es_e[pos] = e;
  es_src[pos] = s;
  es_dst[pos] = dst[e];
}

// one-time transpose: w2t[a][o][k] = w2[k][a*32+o]; dest index = i (contiguous writes)
__global__ void k_w2t(const float* __restrict__ w2, float* __restrict__ w2t) {
  int i = blockIdx.x * 256 + threadIdx.x;
  if (i >= 65536) return;
  int k = i & 63, oa = i >> 6;
  int o = oa & 31, a = oa >> 5;
  w2t[i] = w2[(size_t)k * 1024 + a * 32 + o];
}

// fused conv: block of NB=16 nodes; two K-passes (kh=0: k<32, kh=1: k>=32).
// T[n][k][o] = sum_a h[n,a] * w2[k][a][o] built in LDS as Ts[n][o][k-half] (pad 36),
// then edge contraction with b128 row reads + shfl of eh; atomic into agg[dst].
__global__ __launch_bounds__(256, 2) void k_conv2(const float* __restrict__ h,
                                                  const float* __restrict__ eh,
                                                  const float* __restrict__ w2t,
                                                  const float* __restrict__ b2,
                                                  const int* __restrict__ es_e,
                                                  const int* __restrict__ es_src,
                                                  const int* __restrict__ es_dst,
                                                  const int* __restrict__ offs,
                                                  float* __restrict__ agg) {
  __shared__ float Ts[NB][32][36];
  __shared__ float hs[NB][32];
  __shared__ float hb2[NB][32];
  const int n0 = blockIdx.x * NB;
  const int t = threadIdx.x;
  {
    int n = t >> 5, o = t & 31;
    hs[n][o]     = h[(size_t)(n0 + n) * 32 + o];
    hs[n + 8][o] = h[(size_t)(n0 + n + 8) * 32 + o];
  }
  __syncthreads();
  {  // hb2[n][o] = sum_a h[n,a] * b2[a*32+o]
    int n = t >> 5, o = t & 31;
    float a0 = 0.f, a1 = 0.f;
    for (int a = 0; a < 32; ++a) {
      float b = b2[a * 32 + o];
      a0 = fmaf(hs[n][a], b, a0);
      a1 = fmaf(hs[n + 8][a], b, a1);
    }
    hb2[n][o] = a0;
    hb2[n + 8][o] = a1;
  }
  const int og = t >> 3;  // o index for T-compute (0..31)
  const int kq = t & 7;   // k-quad within half (0..7)
  const int kg = t >> 5;  // edge group (0..7)
  const int ol = t & 31;  // o lane for edges
  const int es = offs[n0], ee = offs[n0 + NB];
  const float* wp = w2t + og * 64 + kq * 4;

  for (int kh = 0; kh < 2; ++kh) {
    float4 acc[NB];
#pragma unroll
    for (int n = 0; n < NB; ++n) acc[n] = make_float4(0.f, 0.f, 0.f, 0.f);
    const float* wph = wp + kh * 32;
    for (int a4 = 0; a4 < 8; ++a4) {
      const float* wa = wph + (size_t)(a4 * 4) * 2048;
      float4 w0 = *(const float4*)(wa);
      float4 w1 = *(const float4*)(wa + 2048);
      float4 w2v = *(const float4*)(wa + 4096);
      float4 w3 = *(const float4*)(wa + 6144);
#pragma unroll
      for (int n = 0; n < NB; ++n) {
        float4 hv = *(const float4*)&hs[n][a4 * 4];
        acc[n].x = fmaf(hv.x, w0.x, acc[n].x); acc[n].y = fmaf(hv.x, w0.y, acc[n].y);
        acc[n].z = fmaf(hv.x, w0.z, acc[n].z); acc[n].w = fmaf(hv.x, w0.w, acc[n].w);
        acc[n].x = fmaf(hv.y, w1.x, acc[n].x); acc[n].y = fmaf(hv.y, w1.y, acc[n].y);
        acc[n].z = fmaf(hv.y, w1.z, acc[n].z); acc[n].w = fmaf(hv.y, w1.w, acc[n].w);
        acc[n].x = fmaf(hv.z, w2v.x, acc[n].x); acc[n].y = fmaf(hv.z, w2v.y, acc[n].y);
        acc[n].z = fmaf(hv.z, w2v.z, acc[n].z); acc[n].w = fmaf(hv.z, w2v.w, acc[n].w);
        acc[n].x = fmaf(hv.w, w3.x, acc[n].x); acc[n].y = fmaf(hv.w, w3.y, acc[n].y);
        acc[n].z = fmaf(hv.w, w3.z, acc[n].z); acc[n].w = fmaf(hv.w, w3.w, acc[n].w);
      }
    }
    if (kh) __syncthreads();  // pass-0 edge reads must finish before Ts overwrite
#pragma unroll
    for (int n = 0; n < NB; ++n) *(float4*)&Ts[n][og][kq * 4] = acc[n];
    __syncthreads();
    for (int ei = es + kg; ei < ee; ei += 8) {
      const int e = es_e[ei];
      const int nl = es_src[ei] - n0;
      const int d = es_dst[ei];
      const float ehv = eh[(size_t)e * 64 + kh * 32 + ol];
      float m = kh ? 0.f : hb2[nl][ol];
      const float* tp = &Ts[nl][ol][0];
#pragma unroll
      for (int j4 = 0; j4 < 8; ++j4) {
        float4 tv = *(const float4*)(tp + j4 * 4);
        m = fmaf(__shfl(ehv, j4 * 4 + 0, 32), tv.x, m);
        m = fmaf(__shfl(ehv, j4 * 4 + 1, 32), tv.y, m);
        m = fmaf(__shfl(ehv, j4 * 4 + 2, 32), tv.z, m);
        m = fmaf(__shfl(ehv, j4 * 4 + 3, 32), tv.w, m);
      }
      atomicAdd(&agg[(size_t)d * 32 + ol], m);
    }
  }
}

// GRU cell, in-place h update. m = relu(agg/denom)
__global__ __launch_bounds__(256) void k_gru(float* __restrict__ h, const float* __restrict__ agg,
                                             const float* __restrict__ denom,
                                             const float* __restrict__ Wih, const float* __restrict__ Whh,
                                             const float* __restrict__ bih, const float* __restrict__ bhh) {
  __shared__ float wih_s[96 * 32];
  __shared__ float whh_s[96 * 32];
  __shared__ float bih_s[96], bhh_s[96];
  for (int i = threadIdx.x; i < 96 * 32; i += 256) { wih_s[i] = Wih[i]; whh_s[i] = Whh[i]; }
  for (int i = threadIdx.x; i < 96; i += 256) { bih_s[i] = bih[i]; bhh_s[i] = bhh[i]; }
  __syncthreads();
  int n = blockIdx.x * 256 + threadIdx.x;
  if (n >= kN) return;
  float dn = fmaxf(denom[n], 1.0f);
  float m[32], hv[32];
  const float4* ap = (const float4*)(agg + (size_t)n * 32);
  const float4* hp = (const float4*)(h + (size_t)n * 32);
#pragma unroll
  for (int i = 0; i < 8; ++i) {
    float4 a = ap[i];
    m[4 * i + 0] = fmaxf(a.x / dn, 0.f);
    m[4 * i + 1] = fmaxf(a.y / dn, 0.f);
    m[4 * i + 2] = fmaxf(a.z / dn, 0.f);
    m[4 * i + 3] = fmaxf(a.w / dn, 0.f);
    float4 b = hp[i];
    hv[4 * i + 0] = b.x; hv[4 * i + 1] = b.y; hv[4 * i + 2] = b.z; hv[4 * i + 3] = b.w;
  }
  float rr[32], zz[32];
#pragma unroll 4
  for (int j = 0; j < 32; ++j) {
    float accA = bih_s[j], accB = bhh_s[j];
    const float4* wi = (const float4*)&wih_s[j * 32];
    const float4* wh = (const float4*)&whh_s[j * 32];
#pragma unroll
    for (int i = 0; i < 8; ++i) {
      float4 a = wi[i], b = wh[i];
      accA = fmaf(m[4 * i + 0], a.x, accA); accA = fmaf(m[4 * i + 1], a.y, accA);
      accA = fmaf(m[4 * i + 2], a.z, accA); accA = fmaf(m[4 * i + 3], a.w, accA);
      accB = fmaf(hv[4 * i + 0], b.x, accB); accB = fmaf(hv[4 * i + 1], b.y, accB);
      accB = fmaf(hv[4 * i + 2], b.z, accB); accB = fmaf(hv[4 * i + 3], b.w, accB);
    }
    rr[j] = sigmoidf_(accA + accB);
  }
#pragma unroll 4
  for (int j = 0; j < 32; ++j) {
    int row = 32 + j;
    float accA = bih_s[row], accB = bhh_s[row];
    const float4* wi = (const float4*)&wih_s[row * 32];
    const float4* wh = (const float4*)&whh_s[row * 32];
#pragma unroll
    for (int i = 0; i < 8; ++i) {
      float4 a = wi[i], b = wh[i];
      accA = fmaf(m[4 * i + 0], a.x, accA); accA = fmaf(m[4 * i + 1], a.y, accA);
      accA = fmaf(m[4 * i + 2], a.z, accA); accA = fmaf(m[4 * i + 3], a.w, accA);
      accB = fmaf(hv[4 * i + 0], b.x, accB); accB = fmaf(hv[4 * i + 1], b.y, accB);
      accB = fmaf(hv[4 * i + 2], b.z, accB); accB = fmaf(hv[4 * i + 3], b.w, accB);
    }
    zz[j] = sigmoidf_(accA + accB);
  }
#pragma unroll 4
  for (int j = 0; j < 32; ++j) {
    int row = 64 + j;
    float accA = bih_s[row], accB = bhh_s[row];
    const float4* wi = (const float4*)&wih_s[row * 32];
    const float4* wh = (const float4*)&whh_s[row * 32];
#pragma unroll
    for (int i = 0; i < 8; ++i) {
      float4 a = wi[i], b = wh[i];
      accA = fmaf(m[4 * i + 0], a.x, accA); accA = fmaf(m[4 * i + 1], a.y, accA);
      accA = fmaf(m[4 * i + 2], a.z, accA); accA = fmaf(m[4 * i + 3], a.w, accA);
      accB = fmaf(hv[4 * i + 0], b.x, accB); accB = fmaf(hv[4 * i + 1], b.y, accB);
      accB = fmaf(hv[4 * i + 2], b.z, accB); accB = fmaf(hv[4 * i + 3], b.w, accB);
    }
    float ng = tanhf(accA + rr[j] * accB);
    zz[j] = (1.f - zz[j]) * ng + zz[j] * hv[j];
  }
  float4* hw = (float4*)(h + (size_t)n * 32);
#pragma unroll
  for (int i = 0; i < 8; ++i)
    hw[i] = make_float4(zz[4 * i + 0], zz[4 * i + 1], zz[4 * i + 2], zz[4 * i + 3]);
}

// fused Set2Set (3 steps of LSTM + softmax attention pooling) + prediction.
// one wave per graph, 4 graphs per 256-thread block. LSTM state in registers:
// lane<32 holds c,hl for feature j=lane; all lanes compute 2 gate rows (lane, lane+64).
__global__ __launch_bounds__(256) void k_s2s(const float* __restrict__ h,
                                             const int* __restrict__ starts,
                                             const float* __restrict__ lwih,
                                             const float* __restrict__ lwhh,
                                             const float* __restrict__ lbih,
                                             const float* __restrict__ lbhh,
                                             const float* __restrict__ pw,
                                             const float* __restrict__ pb,
                                             float* __restrict__ out) {
  __shared__ float wih_s[128][65];
  __shared__ float whh_s[128][33];
  __shared__ float bsum[128];
  for (int i = threadIdx.x; i < 128 * 64; i += 256) wih_s[i >> 6][i & 63] = lwih[i];
  for (int i = threadIdx.x; i < 128 * 32; i += 256) whh_s[i >> 5][i & 31] = lwhh[i];
  for (int i = threadIdx.x; i < 128; i += 256) bsum[i] = lbih[i] + lbhh[i];
  __syncthreads();
  const int g = blockIdx.x * 4 + (threadIdx.x >> 6);
  if (g >= kG) return;
  const int lane = threadIdx.x & 63;
  const int o = lane & 31;
  const int r1 = lane, r2 = lane + 64;
  const int s = starts[g], e = starts[g + 1];
  float c = 0.f, hl = 0.f, rp = 0.f;
  for (int step = 0; step < 3; ++step) {
    float v1 = bsum[r1], v2 = bsum[r2];
    for (int i = 0; i < 32; ++i) {
      float hli = __shfl(hl, i, 64);
      float rpi = __shfl(rp, i, 64);
      v1 = fmaf(wih_s[r1][i], hli, v1);
      v1 = fmaf(wih_s[r1][32 + i], rpi, v1);
      v1 = fmaf(whh_s[r1][i], hli, v1);
      v2 = fmaf(wih_s[r2][i], hli, v2);
      v2 = fmaf(wih_s[r2][32 + i], rpi, v2);
      v2 = fmaf(whh_s[r2][i], hli, v2);
    }
    // lane<32: v1 = i-gate(o), v2 = g-gate(o); lane>=32: v1 = f-gate(o), v2 = o-gate(o)
    float fg = sigmoidf_(__shfl(v1, 32 + o, 64));
    float og_ = sigmoidf_(__shfl(v2, 32 + o, 64));
    float ig = sigmoidf_(v1);
    float gg = tanhf(v2);
    c = fg * c + ig * gg;      // meaningful on lanes<32 only
    hl = og_ * tanhf(c);
    // softmax attention over this graph's nodes
    float q = __shfl(hl, o, 64);
    float mx = -3.0e38f;
    for (int nn = s; nn < e; nn += 2) {
      int n = nn + (lane >> 5);
      float val = (n < e) ? h[(size_t)n * 32 + o] * q : 0.f;
#pragma unroll
      for (int d = 16; d; d >>= 1) val += __shfl_xor(val, d, 32);
      if (n < e) mx = fmaxf(mx, val);
    }
    mx = fmaxf(mx, __shfl_xor(mx, 32, 64));
    float den = 0.f, racc = 0.f;
    for (int nn = s; nn < e; nn += 2) {
      int n = nn + (lane >> 5);
      float hvo = 0.f, val = 0.f;
      if (n < e) { hvo = h[(size_t)n * 32 + o]; val = hvo * q; }
#pragma unroll
      for (int d = 16; d; d >>= 1) val += __shfl_xor(val, d, 32);
      if (n < e) { float p = expf(val - mx); den += p; racc = fmaf(p, hvo, racc); }
    }
    den += __shfl_xor(den, 32, 64);
    racc += __shfl_xor(racc, 32, 64);
    rp = (e > s) ? racc / den : 0.f;  // valid on all lanes
  }
  float acc = __shfl(hl, o, 64) * pw[o] + rp * pw[32 + o];
#pragma unroll
  for (int d = 16; d; d >>= 1) acc += __shfl_xor(acc, d, 32);
  if (lane == 0) out[g] = acc + pb[0];
}

}  // namespace

extern "C" void kernel_launch(void* const* d_in, const int* in_sizes, int n_in,
                              void* d_out, int out_size, void* d_ws, size_t ws_size,
                              hipStream_t stream) {
  const float* x     = (const float*)d_in[0];
  const int*   eidx  = (const int*)d_in[1];
  const float* eattr = (const float*)d_in[2];
  const int*   batch = (const int*)d_in[3];
  const float* lin_w = (const float*)d_in[4];
  const float* lin_b = (const float*)d_in[5];
  const float* e_w1  = (const float*)d_in[6];
  const float* e_b1  = (const float*)d_in[7];
  const float* e_w2  = (const float*)d_in[8];
  const float* e_b2  = (const float*)d_in[9];
  const float* gwih  = (const float*)d_in[10];
  const float* gwhh  = (const float*)d_in[11];
  const float* gbih  = (const float*)d_in[12];
  const float* gbhh  = (const float*)d_in[13];
  const float* lwih  = (const float*)d_in[14];
  const float* lwhh  = (const float*)d_in[15];
  const float* lbih  = (const float*)d_in[16];
  const float* lbhh  = (const float*)d_in[17];
  const float* pw    = (const float*)d_in[18];
  const float* pb    = (const float*)d_in[19];
  const int* srcp = eidx;
  const int* dstp = eidx + kE;

  float* ws = (float*)d_ws;
  size_t off = 0;
  auto alloc = [&](size_t nel) {
    float* p = ws + off;
    off += (nel + 255) & ~(size_t)255;
    return p;
  };
  float* hbuf  = alloc((size_t)kN * 32);
  float* agg   = alloc((size_t)kN * 32);
  float* denom = alloc(kN);
  float* ehb   = alloc((size_t)kE * 64);
  float* w2t   = alloc(65536);
  int* starts  = (int*)alloc(kG + 1);
  int* cnt     = (int*)alloc(kN);
  int* cur     = (int*)alloc(kN);
  int* offs    = (int*)alloc(kN + 1);
  int* es_e    = (int*)alloc(kE);
  int* es_src  = (int*)alloc(kE);
  int* es_dst  = (int*)alloc(kE);
  if (ws_size / 4 < off) return;

  hipMemsetAsync(denom, 0, (size_t)kN * 4, stream);
  hipMemsetAsync(cnt, 0, (size_t)kN * 4, stream);
  hipMemsetAsync(cur, 0, (size_t)kN * 4, stream);

  k_starts<<<(kG + 1 + 255) / 256, 256, 0, stream>>>(batch, starts);
  k_node_init<<<(kN + 255) / 256, 256, 0, stream>>>(x, lin_w, lin_b, hbuf);
  k_edge_h<<<(kE + 255) / 256, 256, 0, stream>>>(eattr, e_w1, e_b1, ehb);
  k_deg_hist<<<(kE + 255) / 256, 256, 0, stream>>>(dstp, srcp, denom, cnt);
  k_scan<<<1, 1024, 0, stream>>>(cnt, offs);
  k_scatter<<<(kE + 255) / 256, 256, 0, stream>>>(srcp, dstp, offs, cur, es_e, es_src, es_dst);
  k_w2t<<<65536 / 256, 256, 0, stream>>>(e_w2, w2t);

  for (int step = 0; step < 3; ++step) {
    hipMemsetAsync(agg, 0, (size_t)kN * 32 * 4, stream);
    k_conv2<<<kN / NB, 256, 0, stream>>>(hbuf, ehb, w2t, e_b2, es_e, es_src, es_dst, offs, agg);
    k_gru<<<(kN + 255) / 256, 256, 0, stream>>>(hbuf, agg, denom, gwih, gwhh, gbih, gbhh);
  }

  k_s2s<<<(kG + 3) / 4, 256, 0, stream>>>(hbuf, starts, lwih, lwhh, lbih, lbhh, pw, pb,
                                          (float*)d_out);
}

// Round 4
// 1003.815 us; speedup vs baseline: 1.0945x; 1.0945x over previous
//
#include <hip/hip_runtime.h>
#include <hip/hip_bf16.h>

namespace {
constexpr int kN = 50000;   // nodes
constexpr int kE = 250000;  // edges
constexpr int kG = 2500;    // graphs
constexpr int NB = 8;       // nodes per conv block

__device__ __forceinline__ float sigmoidf_(float x) { return 1.0f / (1.0f + expf(-x)); }

// starts[g] = first node index with batch[n] >= g (batch is sorted). g in [0, kG].
__global__ void k_starts(const int* __restrict__ batch, int* __restrict__ starts) {
  int g = blockIdx.x * blockDim.x + threadIdx.x;
  if (g > kG) return;
  int lo = 0, hi = kN;
  while (lo < hi) {
    int mid = (lo + hi) >> 1;
    if (batch[mid] < g) lo = mid + 1; else hi = mid;
  }
  starts[g] = lo;
}

// h[n,:] = relu(x[n,:] @ lin_w + lin_b)   [N,32] = [N,32]@[32,32]
__global__ __launch_bounds__(256) void k_node_init(const float* __restrict__ x,
                                                   const float* __restrict__ lin_w,
                                                   const float* __restrict__ lin_b,
                                                   float* __restrict__ h) {
  __shared__ float ws[32 * 32];
  __shared__ float bs[32];
  for (int i = threadIdx.x; i < 1024; i += 256) ws[i] = lin_w[i];
  if (threadIdx.x < 32) bs[threadIdx.x] = lin_b[threadIdx.x];
  __syncthreads();
  int n = blockIdx.x * 256 + threadIdx.x;
  if (n >= kN) return;
  float xv[32];
  const float4* xp = (const float4*)(x + (size_t)n * 32);
#pragma unroll
  for (int i = 0; i < 8; ++i) {
    float4 v = xp[i];
    xv[4 * i + 0] = v.x; xv[4 * i + 1] = v.y; xv[4 * i + 2] = v.z; xv[4 * i + 3] = v.w;
  }
  float acc[32];
#pragma unroll
  for (int o = 0; o < 32; ++o) acc[o] = bs[o];
  for (int i = 0; i < 32; ++i) {
    float a = xv[i];
    const float4* wr = (const float4*)&ws[i * 32];
#pragma unroll
    for (int o4 = 0; o4 < 8; ++o4) {
      float4 w = wr[o4];
      acc[4 * o4 + 0] = fmaf(a, w.x, acc[4 * o4 + 0]);
      acc[4 * o4 + 1] = fmaf(a, w.y, acc[4 * o4 + 1]);
      acc[4 * o4 + 2] = fmaf(a, w.z, acc[4 * o4 + 2]);
      acc[4 * o4 + 3] = fmaf(a, w.w, acc[4 * o4 + 3]);
    }
  }
  float4* hp = (float4*)(h + (size_t)n * 32);
#pragma unroll
  for (int i = 0; i < 8; ++i) {
    float4 v;
    v.x = fmaxf(acc[4 * i + 0], 0.f);
    v.y = fmaxf(acc[4 * i + 1], 0.f);
    v.z = fmaxf(acc[4 * i + 2], 0.f);
    v.w = fmaxf(acc[4 * i + 3], 0.f);
    hp[i] = v;
  }
}

// eh row = relu(edge_attr[e,:] @ e_w1 + e_b1), written to SRC-SORTED position.
__global__ __launch_bounds__(256) void k_edge_h(const float* __restrict__ ea,
                                                const float* __restrict__ w1,
                                                const float* __restrict__ b1,
                                                const int* __restrict__ pos_of_e,
                                                float* __restrict__ ehs) {
  __shared__ float ws[16 * 64];
  __shared__ float bs[64];
  for (int i = threadIdx.x; i < 1024; i += 256) ws[i] = w1[i];
  if (threadIdx.x < 64) bs[threadIdx.x] = b1[threadIdx.x];
  __syncthreads();
  int e = blockIdx.x * 256 + threadIdx.x;
  if (e >= kE) return;
  float av[16];
  const float4* ap = (const float4*)(ea + (size_t)e * 16);
#pragma unroll
  for (int i = 0; i < 4; ++i) {
    float4 v = ap[i];
    av[4 * i + 0] = v.x; av[4 * i + 1] = v.y; av[4 * i + 2] = v.z; av[4 * i + 3] = v.w;
  }
  float acc[64];
#pragma unroll
  for (int o = 0; o < 64; ++o) acc[o] = bs[o];
  for (int i = 0; i < 16; ++i) {
    float a = av[i];
    const float4* wr = (const float4*)&ws[i * 64];
#pragma unroll
    for (int o4 = 0; o4 < 16; ++o4) {
      float4 w = wr[o4];
      acc[4 * o4 + 0] = fmaf(a, w.x, acc[4 * o4 + 0]);
      acc[4 * o4 + 1] = fmaf(a, w.y, acc[4 * o4 + 1]);
      acc[4 * o4 + 2] = fmaf(a, w.z, acc[4 * o4 + 2]);
      acc[4 * o4 + 3] = fmaf(a, w.w, acc[4 * o4 + 3]);
    }
  }
  float4* op = (float4*)(ehs + (size_t)pos_of_e[e] * 64);
#pragma unroll
  for (int i = 0; i < 16; ++i) {
    float4 v;
    v.x = fmaxf(acc[4 * i + 0], 0.f);
    v.y = fmaxf(acc[4 * i + 1], 0.f);
    v.z = fmaxf(acc[4 * i + 2], 0.f);
    v.w = fmaxf(acc[4 * i + 3], 0.f);
    op[i] = v;
  }
}

// histograms: edge count by src (sort key) and by dst (agg denominator/sort)
__global__ void k_hist2(const int* __restrict__ src, const int* __restrict__ dst,
                        int* __restrict__ cnt_s, int* __restrict__ cnt_d) {
  int e = blockIdx.x * blockDim.x + threadIdx.x;
  if (e < kE) {
    atomicAdd(&cnt_s[src[e]], 1);
    atomicAdd(&cnt_d[dst[e]], 1);
  }
}

// exclusive scan; grid=2: block 0 scans cnt_s->offs_s, block 1 scans cnt_d->offs_d
__global__ __launch_bounds__(1024) void k_scan2(const int* __restrict__ cnt_s, int* __restrict__ offs_s,
                                                const int* __restrict__ cnt_d, int* __restrict__ offs_d) {
  const int* cnt = blockIdx.x ? cnt_d : cnt_s;
  int* offs = blockIdx.x ? offs_d : offs_s;
  __shared__ int wsum[16];
  __shared__ int wpre[16];
  __shared__ int carry_s;
  const int tid = threadIdx.x;
  const int lane = tid & 63, wv = tid >> 6;
  if (tid == 0) carry_s = 0;
  __syncthreads();
  for (int base = 0; base < kN; base += 1024) {
    int i = base + tid;
    int v = (i < kN) ? cnt[i] : 0;
    int x = v;
#pragma unroll
    for (int d = 1; d < 64; d <<= 1) {
      int t = __shfl_up(x, d, 64);
      if (lane >= d) x += t;
    }
    if (lane == 63) wsum[wv] = x;
    __syncthreads();
    if (wv == 0) {
      int y = (lane < 16) ? wsum[lane] : 0;
#pragma unroll
      for (int d = 1; d < 16; d <<= 1) {
        int t = __shfl_up(y, d, 64);
        if (lane >= d && lane < 16) y += t;
      }
      if (lane < 16) wpre[lane] = y - wsum[lane];
    }
    __syncthreads();
    int carry = carry_s;
    if (i < kN) offs[i] = carry + wpre[wv] + (x - v);
    __syncthreads();
    if (tid == 0) carry_s = carry + wpre[15] + wsum[15];
    __syncthreads();
  }
  if (tid == 0) offs[kN] = carry_s;
}

__global__ void k_scatter_s(const int* __restrict__ src, const int* __restrict__ dst,
                            const int* __restrict__ offs, int* __restrict__ cur,
                            unsigned char* __restrict__ es_nl, int* __restrict__ es_dst,
                            int* __restrict__ pos_of_e) {
  int e = blockIdx.x * blockDim.x + threadIdx.x;
  if (e >= kE) return;
  int s = src[e];
  int pos = offs[s] + atomicAdd(&cur[s], 1);
  es_nl[pos] = (unsigned char)(s & (NB - 1));
  es_dst[pos] = dst[e];
  pos_of_e[e] = pos;
}

__global__ void k_scatter_d(const int* __restrict__ es_dst, const int* __restrict__ offs_d,
                            int* __restrict__ cur_d, int* __restrict__ ed_pos) {
  int ei = blockIdx.x * blockDim.x + threadIdx.x;
  if (ei >= kE) return;
  int d = es_dst[ei];
  int pd = offs_d[d] + atomicAdd(&cur_d[d], 1);
  ed_pos[pd] = ei;
}

// one-time transpose: w2t[a][o][k] = w2[k][a*32+o]; dest index = i (contiguous writes)
__global__ void k_w2t(const float* __restrict__ w2, float* __restrict__ w2t) {
  int i = blockIdx.x * 256 + threadIdx.x;
  if (i >= 65536) return;
  int k = i & 63, oa = i >> 6;
  int o = oa & 31, a = oa >> 5;
  w2t[i] = w2[(size_t)k * 1024 + a * 32 + o];
}

// fused conv: block of NB=8 nodes; two K-passes (kh=0: k<32, kh=1: k>=32).
// T[n][k][o] = sum_a h[n,a]*w2[k][a][o] built in LDS as Ts[n][o][k-half] (pad 36),
// edge loop reads src-sorted ehs (streamed) and writes msgbuf[ei] (no atomics).
__global__ __launch_bounds__(256, 4) void k_conv3(const float* __restrict__ h,
                                                  const float* __restrict__ ehs,
                                                  const float* __restrict__ w2t,
                                                  const float* __restrict__ b2,
                                                  const unsigned char* __restrict__ es_nl,
                                                  const int* __restrict__ offs,
                                                  float* __restrict__ msgbuf) {
  __shared__ float Ts[NB][32][36];
  __shared__ float hs[NB][32];
  __shared__ float hb2[NB][32];
  const int n0 = blockIdx.x * NB;
  const int t = threadIdx.x;
  const int nloc = t >> 5, o32 = t & 31;
  hs[nloc][o32] = h[(size_t)(n0 + nloc) * 32 + o32];
  __syncthreads();
  {  // hb2[n][o] = sum_a h[n,a] * b2[a*32+o]
    float a0 = 0.f;
#pragma unroll 8
    for (int a = 0; a < 32; ++a) a0 = fmaf(hs[nloc][a], b2[a * 32 + o32], a0);
    hb2[nloc][o32] = a0;
  }
  const int og = t >> 3;  // o (0..31) for T-build
  const int kq = t & 7;   // k-quad within half
  const int es = offs[n0], ee = offs[n0 + NB];
  const float* wp = w2t + og * 64 + kq * 4;

  for (int kh = 0; kh < 2; ++kh) {
    float4 acc[NB];
#pragma unroll
    for (int n = 0; n < NB; ++n) acc[n] = make_float4(0.f, 0.f, 0.f, 0.f);
    const float* wph = wp + kh * 32;
#pragma unroll 2
    for (int a4 = 0; a4 < 8; ++a4) {
      const float* wa = wph + (size_t)(a4 * 4) * 2048;
      float4 w0 = *(const float4*)(wa);
      float4 w1 = *(const float4*)(wa + 2048);
      float4 w2v = *(const float4*)(wa + 4096);
      float4 w3 = *(const float4*)(wa + 6144);
#pragma unroll
      for (int n = 0; n < NB; ++n) {
        float4 hv = *(const float4*)&hs[n][a4 * 4];
        acc[n].x = fmaf(hv.x, w0.x, acc[n].x); acc[n].y = fmaf(hv.x, w0.y, acc[n].y);
        acc[n].z = fmaf(hv.x, w0.z, acc[n].z); acc[n].w = fmaf(hv.x, w0.w, acc[n].w);
        acc[n].x = fmaf(hv.y, w1.x, acc[n].x); acc[n].y = fmaf(hv.y, w1.y, acc[n].y);
        acc[n].z = fmaf(hv.y, w1.z, acc[n].z); acc[n].w = fmaf(hv.y, w1.w, acc[n].w);
        acc[n].x = fmaf(hv.z, w2v.x, acc[n].x); acc[n].y = fmaf(hv.z, w2v.y, acc[n].y);
        acc[n].z = fmaf(hv.z, w2v.z, acc[n].z); acc[n].w = fmaf(hv.z, w2v.w, acc[n].w);
        acc[n].x = fmaf(hv.w, w3.x, acc[n].x); acc[n].y = fmaf(hv.w, w3.y, acc[n].y);
        acc[n].z = fmaf(hv.w, w3.z, acc[n].z); acc[n].w = fmaf(hv.w, w3.w, acc[n].w);
      }
    }
    if (kh) __syncthreads();  // pass-0 edge reads must finish before Ts overwrite
#pragma unroll
    for (int n = 0; n < NB; ++n) *(float4*)&Ts[n][og][kq * 4] = acc[n];
    __syncthreads();
    const int kg = t >> 5;
#pragma unroll 2
    for (int ei = es + kg; ei < ee; ei += 8) {
      const int nl = es_nl[ei];
      const float ehv = ehs[(size_t)ei * 64 + kh * 32 + o32];
      float m = kh ? msgbuf[(size_t)ei * 32 + o32] : hb2[nl][o32];
      const float* tp = &Ts[nl][o32][0];
#pragma unroll
      for (int j4 = 0; j4 < 8; ++j4) {
        float4 tv = *(const float4*)(tp + j4 * 4);
        m = fmaf(__shfl(ehv, j4 * 4 + 0, 32), tv.x, m);
        m = fmaf(__shfl(ehv, j4 * 4 + 1, 32), tv.y, m);
        m = fmaf(__shfl(ehv, j4 * 4 + 2, 32), tv.z, m);
        m = fmaf(__shfl(ehv, j4 * 4 + 3, 32), tv.w, m);
      }
      msgbuf[(size_t)ei * 32 + o32] = m;
    }
  }
}

// per-dst aggregation (no atomics): m_out[d,:] = relu(sum_{e->d} msg[e,:] / max(deg,1))
__global__ __launch_bounds__(256) void k_agg(const float* __restrict__ msgbuf,
                                             const int* __restrict__ ed_pos,
                                             const int* __restrict__ offs_d,
                                             float* __restrict__ m_out) {
  int d = blockIdx.x * 8 + (threadIdx.x >> 5);
  if (d >= kN) return;
  int o = threadIdx.x & 31;
  int s = offs_d[d], e = offs_d[d + 1];
  float acc = 0.f;
  int j = s;
  for (; j + 1 < e; j += 2) {
    int p0 = ed_pos[j], p1 = ed_pos[j + 1];
    acc += msgbuf[(size_t)p0 * 32 + o] + msgbuf[(size_t)p1 * 32 + o];
  }
  if (j < e) acc += msgbuf[(size_t)ed_pos[j] * 32 + o];
  float dn = (float)(e - s);
  if (dn < 1.f) dn = 1.f;
  m_out[(size_t)d * 32 + o] = fmaxf(acc / dn, 0.f);
}

// GRU cell, in-place h update; m is already relu(agg/denom)
__global__ __launch_bounds__(256) void k_gru(float* __restrict__ h, const float* __restrict__ m_in,
                                             const float* __restrict__ Wih, const float* __restrict__ Whh,
                                             const float* __restrict__ bih, const float* __restrict__ bhh) {
  __shared__ float wih_s[96 * 32];
  __shared__ float whh_s[96 * 32];
  __shared__ float bih_s[96], bhh_s[96];
  for (int i = threadIdx.x; i < 96 * 32; i += 256) { wih_s[i] = Wih[i]; whh_s[i] = Whh[i]; }
  for (int i = threadIdx.x; i < 96; i += 256) { bih_s[i] = bih[i]; bhh_s[i] = bhh[i]; }
  __syncthreads();
  int n = blockIdx.x * 256 + threadIdx.x;
  if (n >= kN) return;
  float m[32], hv[32];
  const float4* ap = (const float4*)(m_in + (size_t)n * 32);
  const float4* hp = (const float4*)(h + (size_t)n * 32);
#pragma unroll
  for (int i = 0; i < 8; ++i) {
    float4 a = ap[i];
    m[4 * i + 0] = a.x; m[4 * i + 1] = a.y; m[4 * i + 2] = a.z; m[4 * i + 3] = a.w;
    float4 b = hp[i];
    hv[4 * i + 0] = b.x; hv[4 * i + 1] = b.y; hv[4 * i + 2] = b.z; hv[4 * i + 3] = b.w;
  }
  float rr[32], zz[32];
#pragma unroll 4
  for (int j = 0; j < 32; ++j) {
    float accA = bih_s[j], accB = bhh_s[j];
    const float4* wi = (const float4*)&wih_s[j * 32];
    const float4* wh = (const float4*)&whh_s[j * 32];
#pragma unroll
    for (int i = 0; i < 8; ++i) {
      float4 a = wi[i], b = wh[i];
      accA = fmaf(m[4 * i + 0], a.x, accA); accA = fmaf(m[4 * i + 1], a.y, accA);
      accA = fmaf(m[4 * i + 2], a.z, accA); accA = fmaf(m[4 * i + 3], a.w, accA);
      accB = fmaf(hv[4 * i + 0], b.x, accB); accB = fmaf(hv[4 * i + 1], b.y, accB);
      accB = fmaf(hv[4 * i + 2], b.z, accB); accB = fmaf(hv[4 * i + 3], b.w, accB);
    }
    rr[j] = sigmoidf_(accA + accB);
  }
#pragma unroll 4
  for (int j = 0; j < 32; ++j) {
    int row = 32 + j;
    float accA = bih_s[row], accB = bhh_s[row];
    const float4* wi = (const float4*)&wih_s[row * 32];
    const float4* wh = (const float4*)&whh_s[row * 32];
#pragma unroll
    for (int i = 0; i < 8; ++i) {
      float4 a = wi[i], b = wh[i];
      accA = fmaf(m[4 * i + 0], a.x, accA); accA = fmaf(m[4 * i + 1], a.y, accA);
      accA = fmaf(m[4 * i + 2], a.z, accA); accA = fmaf(m[4 * i + 3], a.w, accA);
      accB = fmaf(hv[4 * i + 0], b.x, accB); accB = fmaf(hv[4 * i + 1], b.y, accB);
      accB = fmaf(hv[4 * i + 2], b.z, accB); accB = fmaf(hv[4 * i + 3], b.w, accB);
    }
    zz[j] = sigmoidf_(accA + accB);
  }
#pragma unroll 4
  for (int j = 0; j < 32; ++j) {
    int row = 64 + j;
    float accA = bih_s[row], accB = bhh_s[row];
    const float4* wi = (const float4*)&wih_s[row * 32];
    const float4* wh = (const float4*)&whh_s[row * 32];
#pragma unroll
    for (int i = 0; i < 8; ++i) {
      float4 a = wi[i], b = wh[i];
      accA = fmaf(m[4 * i + 0], a.x, accA); accA = fmaf(m[4 * i + 1], a.y, accA);
      accA = fmaf(m[4 * i + 2], a.z, accA); accA = fmaf(m[4 * i + 3], a.w, accA);
      accB = fmaf(hv[4 * i + 0], b.x, accB); accB = fmaf(hv[4 * i + 1], b.y, accB);
      accB = fmaf(hv[4 * i + 2], b.z, accB); accB = fmaf(hv[4 * i + 3], b.w, accB);
    }
    float ng = tanhf(accA + rr[j] * accB);
    zz[j] = (1.f - zz[j]) * ng + zz[j] * hv[j];
  }
  float4* hw = (float4*)(h + (size_t)n * 32);
#pragma unroll
  for (int i = 0; i < 8; ++i)
    hw[i] = make_float4(zz[4 * i + 0], zz[4 * i + 1], zz[4 * i + 2], zz[4 * i + 3]);
}

// fused Set2Set (3 steps of LSTM + softmax attention pooling) + prediction.
__global__ __launch_bounds__(256) void k_s2s(const float* __restrict__ h,
                                             const int* __restrict__ starts,
                                             const float* __restrict__ lwih,
                                             const float* __restrict__ lwhh,
                                             const float* __restrict__ lbih,
                                             const float* __restrict__ lbhh,
                                             const float* __restrict__ pw,
                                             const float* __restrict__ pb,
                                             float* __restrict__ out) {
  __shared__ float wih_s[128][65];
  __shared__ float whh_s[128][33];
  __shared__ float bsum[128];
  for (int i = threadIdx.x; i < 128 * 64; i += 256) wih_s[i >> 6][i & 63] = lwih[i];
  for (int i = threadIdx.x; i < 128 * 32; i += 256) whh_s[i >> 5][i & 31] = lwhh[i];
  for (int i = threadIdx.x; i < 128; i += 256) bsum[i] = lbih[i] + lbhh[i];
  __syncthreads();
  const int g = blockIdx.x * 4 + (threadIdx.x >> 6);
  if (g >= kG) return;
  const int lane = threadIdx.x & 63;
  const int o = lane & 31;
  const int r1 = lane, r2 = lane + 64;
  const int s = starts[g], e = starts[g + 1];
  float c = 0.f, hl = 0.f, rp = 0.f;
  for (int step = 0; step < 3; ++step) {
    float v1 = bsum[r1], v2 = bsum[r2];
    for (int i = 0; i < 32; ++i) {
      float hli = __shfl(hl, i, 64);
      float rpi = __shfl(rp, i, 64);
      v1 = fmaf(wih_s[r1][i], hli, v1);
      v1 = fmaf(wih_s[r1][32 + i], rpi, v1);
      v1 = fmaf(whh_s[r1][i], hli, v1);
      v2 = fmaf(wih_s[r2][i], hli, v2);
      v2 = fmaf(wih_s[r2][32 + i], rpi, v2);
      v2 = fmaf(whh_s[r2][i], hli, v2);
    }
    float fg = sigmoidf_(__shfl(v1, 32 + o, 64));
    float og_ = sigmoidf_(__shfl(v2, 32 + o, 64));
    float ig = sigmoidf_(v1);
    float gg = tanhf(v2);
    c = fg * c + ig * gg;
    hl = og_ * tanhf(c);
    float q = __shfl(hl, o, 64);
    float mx = -3.0e38f;
    for (int nn = s; nn < e; nn += 2) {
      int n = nn + (lane >> 5);
      float val = (n < e) ? h[(size_t)n * 32 + o] * q : 0.f;
#pragma unroll
      for (int d = 16; d; d >>= 1) val += __shfl_xor(val, d, 32);
      if (n < e) mx = fmaxf(mx, val);
    }
    mx = fmaxf(mx, __shfl_xor(mx, 32, 64));
    float den = 0.f, racc = 0.f;
    for (int nn = s; nn < e; nn += 2) {
      int n = nn + (lane >> 5);
      float hvo = 0.f, val = 0.f;
      if (n < e) { hvo = h[(size_t)n * 32 + o]; val = hvo * q; }
#pragma unroll
      for (int d = 16; d; d >>= 1) val += __shfl_xor(val, d, 32);
      if (n < e) { float p = expf(val - mx); den += p; racc = fmaf(p, hvo, racc); }
    }
    den += __shfl_xor(den, 32, 64);
    racc += __shfl_xor(racc, 32, 64);
    rp = (e > s) ? racc / den : 0.f;
  }
  float acc = __shfl(hl, o, 64) * pw[o] + rp * pw[32 + o];
#pragma unroll
  for (int d = 16; d; d >>= 1) acc += __shfl_xor(acc, d, 32);
  if (lane == 0) out[g] = acc + pb[0];
}

}  // namespace

extern "C" void kernel_launch(void* const* d_in, const int* in_sizes, int n_in,
                              void* d_out, int out_size, void* d_ws, size_t ws_size,
                              hipStream_t stream) {
  const float* x     = (const float*)d_in[0];
  const int*   eidx  = (const int*)d_in[1];
  const float* eattr = (const float*)d_in[2];
  const int*   batch = (const int*)d_in[3];
  const float* lin_w = (const float*)d_in[4];
  const float* lin_b = (const float*)d_in[5];
  const float* e_w1  = (const float*)d_in[6];
  const float* e_b1  = (const float*)d_in[7];
  const float* e_w2  = (const float*)d_in[8];
  const float* e_b2  = (const float*)d_in[9];
  const float* gwih  = (const float*)d_in[10];
  const float* gwhh  = (const float*)d_in[11];
  const float* gbih  = (const float*)d_in[12];
  const float* gbhh  = (const float*)d_in[13];
  const float* lwih  = (const float*)d_in[14];
  const float* lwhh  = (const float*)d_in[15];
  const float* lbih  = (const float*)d_in[16];
  const float* lbhh  = (const float*)d_in[17];
  const float* pw    = (const float*)d_in[18];
  const float* pb    = (const float*)d_in[19];
  const int* srcp = eidx;
  const int* dstp = eidx + kE;

  float* ws = (float*)d_ws;
  size_t off = 0;
  auto alloc = [&](size_t nel) {
    float* p = ws + off;
    off += (nel + 255) & ~(size_t)255;
    return p;
  };
  float* hbuf   = alloc((size_t)kN * 32);
  float* mbuf   = alloc((size_t)kN * 32);
  float* ehs    = alloc((size_t)kE * 64);
  float* msgbuf = alloc((size_t)kE * 32);
  float* w2t    = alloc(65536);
  int* starts   = (int*)alloc(kG + 1);
  int* cnt_s    = (int*)alloc(kN);
  int* cnt_d    = (int*)alloc(kN);
  int* cur_s    = (int*)alloc(kN);
  int* cur_d    = (int*)alloc(kN);
  int* offs_s   = (int*)alloc(kN + 1);
  int* offs_d   = (int*)alloc(kN + 1);
  int* es_dst   = (int*)alloc(kE);
  int* pos_of_e = (int*)alloc(kE);
  int* ed_pos   = (int*)alloc(kE);
  unsigned char* es_nl = (unsigned char*)alloc((kE + 3) / 4);
  if (ws_size / 4 < off) return;

  hipMemsetAsync(cnt_s, 0, (size_t)kN * 4, stream);
  hipMemsetAsync(cnt_d, 0, (size_t)kN * 4, stream);
  hipMemsetAsync(cur_s, 0, (size_t)kN * 4, stream);
  hipMemsetAsync(cur_d, 0, (size_t)kN * 4, stream);

  k_starts<<<(kG + 1 + 255) / 256, 256, 0, stream>>>(batch, starts);
  k_node_init<<<(kN + 255) / 256, 256, 0, stream>>>(x, lin_w, lin_b, hbuf);
  k_hist2<<<(kE + 255) / 256, 256, 0, stream>>>(srcp, dstp, cnt_s, cnt_d);
  k_scan2<<<2, 1024, 0, stream>>>(cnt_s, offs_s, cnt_d, offs_d);
  k_scatter_s<<<(kE + 255) / 256, 256, 0, stream>>>(srcp, dstp, offs_s, cur_s, es_nl, es_dst,
                                                    pos_of_e);
  k_edge_h<<<(kE + 255) / 256, 256, 0, stream>>>(eattr, e_w1, e_b1, pos_of_e, ehs);
  k_scatter_d<<<(kE + 255) / 256, 256, 0, stream>>>(es_dst, offs_d, cur_d, ed_pos);
  k_w2t<<<65536 / 256, 256, 0, stream>>>(e_w2, w2t);

  for (int step = 0; step < 3; ++step) {
    k_conv3<<<kN / NB, 256, 0, stream>>>(hbuf, ehs, w2t, e_b2, es_nl, offs_s, msgbuf);
    k_agg<<<(kN + 7) / 8, 256, 0, stream>>>(msgbuf, ed_pos, offs_d, mbuf);
    k_gru<<<(kN + 255) / 256, 256, 0, stream>>>(hbuf, mbuf, gwih, gwhh, gbih, gbhh);
  }

  k_s2s<<<(kG + 3) / 4, 256, 0, stream>>>(hbuf, starts, lwih, lwhh, lbih, lbhh, pw, pb,
                                          (float*)d_out);
}